// Round 1
// baseline (5496.117 us; speedup 1.0000x reference)
//
#include <hip/hip_runtime.h>
#include <hip/hip_bf16.h>
#include <math.h>

#define B_ 4
#define S_ 2048
#define D_ 768
#define H_ 12
#define DH_ 64
#define F_ 3072
#define NTOK (B_*S_)   // 8192
#define BH_ (B_*H_)    // 48

typedef __hip_bfloat16 bf16;

__device__ __forceinline__ float bs2f(short s){
  union { unsigned int u; float f; } cv; cv.u = ((unsigned int)(unsigned short)s) << 16; return cv.f;
}
__device__ __forceinline__ float b2f(bf16 v){ return __bfloat162float(v); }
__device__ __forceinline__ bf16 f2b(float v){ return __float2bfloat16(v); }

// ---------------- fp32 -> bf16 convert ----------------
__global__ void f32_to_bf16_k(const float* __restrict__ in, bf16* __restrict__ out, int n){
  int i = blockIdx.x*256 + threadIdx.x;
  if (i < n) out[i] = f2b(in[i]);
}

// ---------------- pack Wq/Wk/Wv [H,D,Dh] -> Wcat [D, 3*D], biases -> bcat[3*D] ----------------
__global__ void pack_qkv_k(const float* __restrict__ Wq, const float* __restrict__ bq,
                           const float* __restrict__ Wk, const float* __restrict__ bk,
                           const float* __restrict__ Wv, const float* __restrict__ bv,
                           bf16* __restrict__ Wcat, float* __restrict__ bcat){
  int idx = blockIdx.x*256 + threadIdx.x;
  if (idx < D_*3*D_){
    int k = idx / (3*D_);
    int c = idx - k*(3*D_);
    int which = c / D_;
    int cc = c - which*D_;
    int h = cc >> 6, e = cc & 63;
    const float* W = (which==0) ? Wq : ((which==1) ? Wk : Wv);
    Wcat[idx] = f2b(W[((size_t)h*D_ + k)*DH_ + e]);
  }
  if (idx < 3*D_){
    int which = idx / D_;
    int cc = idx - which*D_;
    int h = cc >> 6, e = cc & 63;
    const float* bb = (which==0) ? bq : ((which==1) ? bk : bv);
    bcat[idx] = bb[h*DH_ + e];
  }
}

// ---------------- generic tiled GEMM: C[M,N] = A[M,K] @ B[K,N] (+bias, epilogues) ----------------
// EPI 0: +bias, scatter into q/k/v [B,H,S,Dh]
// EPI 1: +bias +aux (residual), store bf16 C
// EPI 2: +bias, exact GELU, store bf16 C
template<int EPI>
__global__ __launch_bounds__(256) void gemm_k(
    const bf16* __restrict__ A, const bf16* __restrict__ Bm,
    const float* __restrict__ bias, const bf16* __restrict__ aux,
    bf16* __restrict__ C, int M, int N, int K,
    bf16* __restrict__ qb, bf16* __restrict__ kb, bf16* __restrict__ vb)
{
  __shared__ float As[16][68];
  __shared__ float Bs[16][68];
  const int tid = threadIdx.x;
  const int tx = tid & 15, ty = tid >> 4;
  const int m0 = blockIdx.y * 64, n0 = blockIdx.x * 64;
  const int ar = tid >> 2;          // 0..63 row in A-tile
  const int ac = (tid & 3) * 4;     // k-offset 0..12
  const int br = tid >> 4;          // 0..15 k-row in B-tile
  const int bc = (tid & 15) * 4;    // col 0..60
  float acc[4][4];
#pragma unroll
  for (int i=0;i<4;i++)
#pragma unroll
    for (int j=0;j<4;j++) acc[i][j] = 0.f;

  for (int k0 = 0; k0 < K; k0 += 16){
    short4 av  = *reinterpret_cast<const short4*>(A  + (size_t)(m0+ar)*K + (k0+ac));
    short4 bv4 = *reinterpret_cast<const short4*>(Bm + (size_t)(k0+br)*N + (n0+bc));
    As[ac+0][ar] = bs2f(av.x);  As[ac+1][ar] = bs2f(av.y);
    As[ac+2][ar] = bs2f(av.z);  As[ac+3][ar] = bs2f(av.w);
    Bs[br][bc+0] = bs2f(bv4.x); Bs[br][bc+1] = bs2f(bv4.y);
    Bs[br][bc+2] = bs2f(bv4.z); Bs[br][bc+3] = bs2f(bv4.w);
    __syncthreads();
#pragma unroll
    for (int kk=0; kk<16; ++kk){
      float4 a4 = *reinterpret_cast<const float4*>(&As[kk][ty*4]);
      float4 b4 = *reinterpret_cast<const float4*>(&Bs[kk][tx*4]);
      float a[4] = {a4.x,a4.y,a4.z,a4.w};
      float b[4] = {b4.x,b4.y,b4.z,b4.w};
#pragma unroll
      for (int i=0;i<4;i++)
#pragma unroll
        for (int j=0;j<4;j++) acc[i][j] += a[i]*b[j];
    }
    __syncthreads();
  }

#pragma unroll
  for (int i=0;i<4;i++){
    int m = m0 + ty*4 + i;
#pragma unroll
    for (int j=0;j<4;j++){
      int n = n0 + tx*4 + j;
      float v = acc[i][j] + bias[n];
      if (EPI == 0){
        int which = n / D_;
        int cc = n - which*D_;
        int h = cc >> 6, e = cc & 63;
        int b = m >> 11, s = m & (S_-1);
        bf16* dst = (which==0) ? qb : ((which==1) ? kb : vb);
        dst[((size_t)(b*H_ + h)*S_ + s)*DH_ + e] = f2b(v);
      } else if (EPI == 1){
        v += b2f(aux[(size_t)m*N + n]);
        C[(size_t)m*N + n] = f2b(v);
      } else {
        v = 0.5f * v * (1.0f + erff(v * 0.70710678118654752f));
        C[(size_t)m*N + n] = f2b(v);
      }
    }
  }
}

// ---------------- causal attention: one block per (b,h,query-row) ----------------
__global__ __launch_bounds__(256) void attn_k(const bf16* __restrict__ qb,
    const bf16* __restrict__ kb, const bf16* __restrict__ vb, bf16* __restrict__ ctx)
{
  const int qi = blockIdx.x & (S_-1);
  const int bh = blockIdx.x >> 11;
  const int tid = threadIdx.x;
  __shared__ float qs[DH_];
  __shared__ float sc[S_];
  __shared__ float rmax[4], rsum[4];
  __shared__ float part[4][DH_];
  const size_t base = (size_t)bh * S_ * DH_;

  if (tid < DH_) qs[tid] = b2f(qb[base + (size_t)qi*DH_ + tid]);
  __syncthreads();

  const int L = qi + 1;
  float lmax = -1e30f;
  for (int j = tid; j < L; j += 256){
    const bf16* kr = kb + base + (size_t)j*DH_;
    float dot = 0.f;
#pragma unroll
    for (int e = 0; e < DH_; e += 4){
      short4 kv = *reinterpret_cast<const short4*>(kr + e);
      dot += qs[e]*bs2f(kv.x) + qs[e+1]*bs2f(kv.y) + qs[e+2]*bs2f(kv.z) + qs[e+3]*bs2f(kv.w);
    }
    dot *= 0.125f;               // / sqrt(64)
    sc[j] = dot;
    lmax = fmaxf(lmax, dot);
  }
#pragma unroll
  for (int o = 32; o > 0; o >>= 1) lmax = fmaxf(lmax, __shfl_down(lmax, o));
  const int lane = tid & 63, w = tid >> 6;
  if (lane == 0) rmax[w] = lmax;
  __syncthreads();
  const float gmax = fmaxf(fmaxf(rmax[0],rmax[1]), fmaxf(rmax[2],rmax[3]));

  float lsum = 0.f;
  for (int j = tid; j < L; j += 256){
    float p = __expf(sc[j] - gmax);
    sc[j] = p;
    lsum += p;
  }
#pragma unroll
  for (int o = 32; o > 0; o >>= 1) lsum += __shfl_down(lsum, o);
  if (lane == 0) rsum[w] = lsum;
  __syncthreads();
  const float inv = 1.0f / (rsum[0]+rsum[1]+rsum[2]+rsum[3]);

  const int e = tid & 63, g = tid >> 6;
  float acc = 0.f;
  const bf16* vbase = vb + base;
  for (int j = g; j < L; j += 4) acc += sc[j] * b2f(vbase[(size_t)j*DH_ + e]);
  part[g][e] = acc;
  __syncthreads();
  if (tid < DH_){
    float v = (part[0][tid]+part[1][tid]+part[2][tid]+part[3][tid]) * inv;
    int b = bh / H_, h = bh - b*H_;
    ctx[((size_t)(b*S_ + qi))*D_ + h*DH_ + tid] = f2b(v);
  }
}

// ---------------- layernorm over D=768 (3 elems/thread @ 256 threads) ----------------
template<typename T> __device__ __forceinline__ void stf(T* p, float v);
template<> __device__ __forceinline__ void stf<float>(float* p, float v){ *p = v; }
template<> __device__ __forceinline__ void stf<bf16>(bf16* p, float v){ *p = f2b(v); }

template<typename OutT>
__global__ __launch_bounds__(256) void layernorm_k(const bf16* __restrict__ X,
    const float* __restrict__ g, const float* __restrict__ bta, OutT* __restrict__ Y)
{
  const int row = blockIdx.x;
  const int tid = threadIdx.x;
  const bf16* xr = X + (size_t)row * D_;
  float vals[3];
  float s = 0.f, s2 = 0.f;
#pragma unroll
  for (int i = 0; i < 3; i++){
    float v = b2f(xr[tid + i*256]);
    vals[i] = v; s += v; s2 += v*v;
  }
#pragma unroll
  for (int o = 32; o > 0; o >>= 1){ s += __shfl_down(s, o); s2 += __shfl_down(s2, o); }
  __shared__ float rs[4], rq[4];
  const int lane = tid & 63, w = tid >> 6;
  if (lane == 0){ rs[w] = s; rq[w] = s2; }
  __syncthreads();
  s  = rs[0]+rs[1]+rs[2]+rs[3];
  s2 = rq[0]+rq[1]+rq[2]+rq[3];
  const float mean = s * (1.0f/D_);
  const float var  = s2 * (1.0f/D_) - mean*mean;
  const float inv  = rsqrtf(var + 1e-5f);
#pragma unroll
  for (int i = 0; i < 3; i++){
    int c = tid + i*256;
    float o = (vals[i] - mean) * inv * g[c] + bta[c];
    stf(Y + (size_t)row*D_ + c, o);
  }
}

extern "C" void kernel_launch(void* const* d_in, const int* in_sizes, int n_in,
                              void* d_out, int out_size, void* d_ws, size_t ws_size,
                              hipStream_t stream)
{
  const float* x   = (const float*)d_in[0];
  const float* Wq  = (const float*)d_in[1];
  const float* bq  = (const float*)d_in[2];
  const float* Wk  = (const float*)d_in[3];
  const float* bk  = (const float*)d_in[4];
  const float* Wv  = (const float*)d_in[5];
  const float* bv  = (const float*)d_in[6];
  const float* Wo  = (const float*)d_in[7];
  const float* bo  = (const float*)d_in[8];
  const float* W1  = (const float*)d_in[9];
  const float* b1  = (const float*)d_in[10];
  const float* W2  = (const float*)d_in[11];
  const float* b2  = (const float*)d_in[12];
  const float* g1  = (const float*)d_in[13];
  const float* be1 = (const float*)d_in[14];
  const float* g2  = (const float*)d_in[15];
  const float* be2 = (const float*)d_in[16];
  float* out = (float*)d_out;

  char* ws = (char*)d_ws;
  size_t off = 0;
  auto alloc = [&](size_t bytes)->char*{
    char* p = ws + off; off = (off + bytes + 255) & ~(size_t)255; return p;
  };
  bf16*  xb   = (bf16*) alloc((size_t)NTOK*D_*2);     // 12.6 MB
  bf16*  Wcat = (bf16*) alloc((size_t)D_*3*D_*2);     // 3.5 MB
  float* bcat = (float*)alloc((size_t)3*D_*4);
  bf16*  WoB  = (bf16*) alloc((size_t)D_*D_*2);       // 1.2 MB
  bf16*  W1B  = (bf16*) alloc((size_t)D_*F_*2);       // 4.7 MB
  bf16*  W2B  = (bf16*) alloc((size_t)F_*D_*2);       // 4.7 MB
  bf16*  r1   = (bf16*) alloc((size_t)NTOK*F_*2);     // 50.3 MB: qkv then ff1
  bf16*  qb   = r1;
  bf16*  kb   = r1 + (size_t)NTOK*D_;
  bf16*  vb   = r1 + (size_t)2*NTOK*D_;
  bf16*  ff1  = r1;
  bf16*  ctxb = (bf16*) alloc((size_t)NTOK*D_*2);     // 12.6 MB: ctx then y2
  bf16*  y1   = (bf16*) alloc((size_t)NTOK*D_*2);     // 12.6 MB
  bf16*  hb   = (bf16*) alloc((size_t)NTOK*D_*2);     // 12.6 MB
  bf16*  y2   = ctxb;

  // converts + pack
  f32_to_bf16_k<<<(NTOK*D_+255)/256, 256, 0, stream>>>(x,  xb,  NTOK*D_);
  f32_to_bf16_k<<<(D_*D_ +255)/256, 256, 0, stream>>>(Wo, WoB, D_*D_);
  f32_to_bf16_k<<<(D_*F_ +255)/256, 256, 0, stream>>>(W1, W1B, D_*F_);
  f32_to_bf16_k<<<(F_*D_ +255)/256, 256, 0, stream>>>(W2, W2B, F_*D_);
  pack_qkv_k<<<(D_*3*D_+255)/256, 256, 0, stream>>>(Wq,bq,Wk,bk,Wv,bv,Wcat,bcat);

  // 1) fused QKV projection: [8192,768] @ [768,2304]
  gemm_k<0><<<dim3(3*D_/64, NTOK/64), 256, 0, stream>>>(
      xb, Wcat, bcat, nullptr, nullptr, NTOK, 3*D_, D_, qb, kb, vb);

  // 2) causal attention -> ctx [8192,768]
  attn_k<<<BH_*S_, 256, 0, stream>>>(qb, kb, vb, ctxb);

  // 3) out-proj + residual: y1 = ctx@Wo + bo + x
  gemm_k<1><<<dim3(D_/64, NTOK/64), 256, 0, stream>>>(
      ctxb, WoB, bo, xb, y1, NTOK, D_, D_, nullptr, nullptr, nullptr);

  // 4) LN1 -> h
  layernorm_k<bf16><<<NTOK, 256, 0, stream>>>(y1, g1, be1, hb);

  // 5) FF1 + exact GELU: ff1 = gelu(h@W1 + b1)
  gemm_k<2><<<dim3(F_/64, NTOK/64), 256, 0, stream>>>(
      hb, W1B, b1, nullptr, ff1, NTOK, F_, D_, nullptr, nullptr, nullptr);

  // 6) FF2 + residual: y2 = ff1@W2 + b2 + h
  gemm_k<1><<<dim3(D_/64, NTOK/64), 256, 0, stream>>>(
      ff1, W2B, b2, hb, y2, NTOK, D_, F_, nullptr, nullptr, nullptr);

  // 7) LN2 -> out (fp32)
  layernorm_k<float><<<NTOK, 256, 0, stream>>>(y2, g2, be2, out);
}

// Round 2
// 855.062 us; speedup vs baseline: 6.4277x; 6.4277x over previous
//
#include <hip/hip_runtime.h>
#include <hip/hip_bf16.h>
#include <math.h>

#define B_ 4
#define S_ 2048
#define D_ 768
#define H_ 12
#define DH_ 64
#define F_ 3072
#define NTOK (B_*S_)   // 8192
#define BH_ (B_*H_)    // 48

typedef __hip_bfloat16 bf16;
typedef __attribute__((ext_vector_type(8))) short bf16x8;   // 8 bf16 = 4 VGPRs (MFMA A/B frag)
typedef __attribute__((ext_vector_type(4))) float f32x4;    // MFMA C/D frag

__device__ __forceinline__ float bs2f(short s){
  union { unsigned int u; float f; } cv; cv.u = ((unsigned int)(unsigned short)s) << 16; return cv.f;
}
__device__ __forceinline__ float b2f(bf16 v){ return __bfloat162float(v); }
__device__ __forceinline__ bf16 f2b(float v){ return __float2bfloat16(v); }

// ---------------- fp32 -> bf16 convert (row-major copy) ----------------
__global__ void f32_to_bf16_k(const float* __restrict__ in, bf16* __restrict__ out, int n){
  int i = blockIdx.x*256 + threadIdx.x;
  if (i < n) out[i] = f2b(in[i]);
}

// ------- transpose+convert: in[K][N] f32 -> out[N][K] bf16 (LDS 32x32 tiles) -------
__global__ __launch_bounds__(256) void transpose_f32_bf16_k(const float* __restrict__ in,
    bf16* __restrict__ out, int K, int N){
  __shared__ float t[32][33];
  const int kb = blockIdx.y*32, nb = blockIdx.x*32;
  const int x = threadIdx.x & 31, y = threadIdx.x >> 5;   // y = 0..7
#pragma unroll
  for (int yy = y; yy < 32; yy += 8)
    t[yy][x] = in[(size_t)(kb+yy)*N + nb + x];
  __syncthreads();
#pragma unroll
  for (int yy = y; yy < 32; yy += 8)
    out[(size_t)(nb+yy)*K + kb + x] = f2b(t[x][yy]);
}

// ---- pack Wq/Wk/Wv [H,D,Dh] -> WcatT [3D][D] (n-major, k contiguous), biases -> bcat[3D] ----
__global__ void pack_qkv_t_k(const float* __restrict__ Wq, const float* __restrict__ bq,
                             const float* __restrict__ Wk, const float* __restrict__ bk,
                             const float* __restrict__ Wv, const float* __restrict__ bv,
                             bf16* __restrict__ Wt, float* __restrict__ bcat){
  int idx = blockIdx.x*256 + threadIdx.x;
  if (idx < 3*D_*D_){
    int n = idx / D_;
    int k = idx - n*D_;
    int which = n / D_;
    int cc = n - which*D_;
    int h = cc >> 6, e = cc & 63;
    const float* W = (which==0) ? Wq : ((which==1) ? Wk : Wv);
    Wt[idx] = f2b(W[((size_t)h*D_ + k)*DH_ + e]);
  }
  if (idx < 3*D_){
    int which = idx / D_;
    int cc = idx - which*D_;
    int h = cc >> 6, e = cc & 63;
    const float* bb = (which==0) ? bq : ((which==1) ? bk : bv);
    bcat[idx] = bb[h*DH_ + e];
  }
}

// ---------------- MFMA GEMM: C[M,N] = A[M,K] @ Bt[N,K]^T  (+bias, epilogues) ----------------
// 128x128 tile, BK=32, 4 waves in 2x2, each wave 4x4 grid of 16x16x32 MFMAs.
// Verified layouts (learn_hip m89/m97/m120):
//   A frag:  lane holds A[m = lane&15][k = (lane>>4)*8 + j], j=0..7  -> contiguous-k 16B read
//   B frag:  lane holds B[k = (lane>>4)*8 + j][n = lane&15]          -> contiguous-k read of Bt row n
//   C/D:     col = lane&15, row = (lane>>4)*4 + reg
// EPI 0: +bias, scatter into q/k/v [B,H,S,Dh];  EPI 1: +bias+aux residual -> bf16;  EPI 2: +bias, exact GELU -> bf16
template<int EPI>
__global__ __launch_bounds__(256) void mgemm_k(
    const bf16* __restrict__ A, const bf16* __restrict__ Bt,
    const float* __restrict__ bias, const bf16* __restrict__ aux,
    bf16* __restrict__ C, int M, int N, int K,
    bf16* __restrict__ qb, bf16* __restrict__ kb, bf16* __restrict__ vb)
{
  __shared__ bf16 As[128][40];   // +8 pad: 2-way LDS aliasing only (free per m136)
  __shared__ bf16 Bs[128][40];
  const int tid  = threadIdx.x;
  const int wave = tid >> 6, lane = tid & 63;
  const int quad = lane >> 4, l16 = lane & 15;
  const int wm = (wave >> 1) * 64, wn = (wave & 1) * 64;
  const int m0 = blockIdx.y * 128, n0 = blockIdx.x * 128;
  const int sr = tid >> 2;        // 0..63 staging row
  const int sc = (tid & 3) * 8;   // k-offset 0,8,16,24

  f32x4 acc[4][4];
#pragma unroll
  for (int i=0;i<4;i++)
#pragma unroll
    for (int j=0;j<4;j++) acc[i][j] = (f32x4)0.f;

  for (int k0 = 0; k0 < K; k0 += 32){
    __syncthreads();
    *(bf16x8*)&As[sr     ][sc] = *(const bf16x8*)(A  + (size_t)(m0+sr   )*K + k0 + sc);
    *(bf16x8*)&As[sr + 64][sc] = *(const bf16x8*)(A  + (size_t)(m0+sr+64)*K + k0 + sc);
    *(bf16x8*)&Bs[sr     ][sc] = *(const bf16x8*)(Bt + (size_t)(n0+sr   )*K + k0 + sc);
    *(bf16x8*)&Bs[sr + 64][sc] = *(const bf16x8*)(Bt + (size_t)(n0+sr+64)*K + k0 + sc);
    __syncthreads();
    bf16x8 af[4], bf[4];
#pragma unroll
    for (int i=0;i<4;i++) af[i] = *(const bf16x8*)&As[wm + i*16 + l16][quad*8];
#pragma unroll
    for (int j=0;j<4;j++) bf[j] = *(const bf16x8*)&Bs[wn + j*16 + l16][quad*8];
#pragma unroll
    for (int i=0;i<4;i++)
#pragma unroll
      for (int j=0;j<4;j++)
        acc[i][j] = __builtin_amdgcn_mfma_f32_16x16x32_bf16(af[i], bf[j], acc[i][j], 0, 0, 0);
  }

#pragma unroll
  for (int i=0;i<4;i++){
#pragma unroll
    for (int j=0;j<4;j++){
      const int n = n0 + wn + j*16 + l16;
#pragma unroll
      for (int r=0;r<4;r++){
        const int m = m0 + wm + i*16 + quad*4 + r;
        float v = acc[i][j][r] + bias[n];
        if (EPI == 0){
          int which = n / D_;
          int cc = n - which*D_;
          int h = cc >> 6, e = cc & 63;
          int b = m >> 11, s = m & (S_-1);
          bf16* dst = (which==0) ? qb : ((which==1) ? kb : vb);
          dst[((size_t)(b*H_ + h)*S_ + s)*DH_ + e] = f2b(v);
        } else if (EPI == 1){
          v += b2f(aux[(size_t)m*N + n]);
          C[(size_t)m*N + n] = f2b(v);
        } else {
          v = 0.5f * v * (1.0f + erff(v * 0.70710678118654752f));
          C[(size_t)m*N + n] = f2b(v);
        }
      }
    }
  }
}

// ---------------- flash attention (vector): 64-query x 32-key tiles, online softmax ----------------
// block = 256 threads (16x16 grid); thread (tx,ty) owns q rows 4ty..4ty+3.
// QK phase: scores s[4][2] at k cols 2tx..2tx+1. PV phase: O cols e = 4tx..4tx+3.
__global__ __launch_bounds__(256) void fattn_k(const bf16* __restrict__ qb,
    const bf16* __restrict__ kb, const bf16* __restrict__ vb, bf16* __restrict__ ctx)
{
  __shared__ float Qs[64][68];   // [e][q], pre-scaled by 1/8
  __shared__ float Ks[64][34];   // [e][k]
  __shared__ float Vs[32][68];   // [k][e]
  __shared__ float Ps[32][68];   // [k][q]
  const int bh = blockIdx.x;            // 0..47
  const int qt = 31 - blockIdx.y;       // heavy tiles dispatched first
  const int q0 = qt * 64;
  const int tid = threadIdx.x;
  const int tx = tid & 15, ty = tid >> 4;
  const size_t base = (size_t)bh * S_ * DH_;

  { // stage Q tile (once), transposed + pre-scaled
    const int r = tid >> 2;            // 0..63
    const int c = (tid & 3) * 16;      // 0,16,32,48
    const bf16* src = qb + base + (size_t)(q0 + r)*DH_ + c;
    bf16x8 v0 = *(const bf16x8*)(src);
    bf16x8 v1 = *(const bf16x8*)(src + 8);
#pragma unroll
    for (int t=0;t<8;t++) Qs[c+t  ][r] = bs2f(v0[t]) * 0.125f;
#pragma unroll
    for (int t=0;t<8;t++) Qs[c+8+t][r] = bs2f(v1[t]) * 0.125f;
  }

  float mi[4], li[4], o[4][4];
#pragma unroll
  for (int i=0;i<4;i++){
    mi[i] = -1e30f; li[i] = 0.f;
#pragma unroll
    for (int j=0;j<4;j++) o[i][j] = 0.f;
  }

  const int ktiles = 2*qt + 2;
  for (int kt = 0; kt < ktiles; ++kt){
    const int k0 = kt * 32;
    __syncthreads();   // previous PV reads of Ks/Vs done
    { // stage K (transposed) and V (direct), bf16 -> fp32
      const int r = tid >> 3;          // 0..31
      const int c = (tid & 7) * 8;     // 0..56
      bf16x8 kv = *(const bf16x8*)(kb + base + (size_t)(k0 + r)*DH_ + c);
      bf16x8 vv = *(const bf16x8*)(vb + base + (size_t)(k0 + r)*DH_ + c);
#pragma unroll
      for (int t=0;t<8;t++) Ks[c+t][r] = bs2f(kv[t]);
      float4 a = make_float4(bs2f(vv[0]),bs2f(vv[1]),bs2f(vv[2]),bs2f(vv[3]));
      float4 b = make_float4(bs2f(vv[4]),bs2f(vv[5]),bs2f(vv[6]),bs2f(vv[7]));
      *(float4*)&Vs[r][c]   = a;
      *(float4*)&Vs[r][c+4] = b;
    }
    __syncthreads();

    // scores: s[i][j] = (Q/8) . K
    float s[4][2] = {{0.f,0.f},{0.f,0.f},{0.f,0.f},{0.f,0.f}};
#pragma unroll 4
    for (int e = 0; e < 64; ++e){
      float4 qv = *(const float4*)&Qs[e][ty*4];
      float2 kv = *(const float2*)&Ks[e][tx*2];
      s[0][0] += qv.x*kv.x; s[0][1] += qv.x*kv.y;
      s[1][0] += qv.y*kv.x; s[1][1] += qv.y*kv.y;
      s[2][0] += qv.z*kv.x; s[2][1] += qv.z*kv.y;
      s[3][0] += qv.w*kv.x; s[3][1] += qv.w*kv.y;
    }
    if (kt >= 2*qt){ // diagonal region: causal mask
#pragma unroll
      for (int i=0;i<4;i++){
        const int q = q0 + ty*4 + i;
#pragma unroll
        for (int j=0;j<2;j++){
          const int k = k0 + tx*2 + j;
          if (k > q) s[i][j] = -1e30f;
        }
      }
    }

    // online softmax update + write P (transposed) to LDS
#pragma unroll
    for (int i=0;i<4;i++){
      float mx = fmaxf(s[i][0], s[i][1]);
      mx = fmaxf(mx, __shfl_xor(mx, 1));
      mx = fmaxf(mx, __shfl_xor(mx, 2));
      mx = fmaxf(mx, __shfl_xor(mx, 4));
      mx = fmaxf(mx, __shfl_xor(mx, 8));
      const float mnew  = fmaxf(mi[i], mx);
      const float alpha = __expf(mi[i] - mnew);
      const float p0 = __expf(s[i][0] - mnew);
      const float p1 = __expf(s[i][1] - mnew);
      float rs = p0 + p1;
      rs += __shfl_xor(rs, 1);
      rs += __shfl_xor(rs, 2);
      rs += __shfl_xor(rs, 4);
      rs += __shfl_xor(rs, 8);
      li[i] = li[i]*alpha + rs;
      mi[i] = mnew;
      o[i][0]*=alpha; o[i][1]*=alpha; o[i][2]*=alpha; o[i][3]*=alpha;
      Ps[tx*2+0][ty*4+i] = p0;
      Ps[tx*2+1][ty*4+i] = p1;
    }
    __syncthreads();

    // PV: o[i][j] += P[q][k] * V[k][e]
#pragma unroll 4
    for (int kk = 0; kk < 32; ++kk){
      float4 pv = *(const float4*)&Ps[kk][ty*4];
      float4 vv = *(const float4*)&Vs[kk][tx*4];
      o[0][0] += pv.x*vv.x; o[0][1] += pv.x*vv.y; o[0][2] += pv.x*vv.z; o[0][3] += pv.x*vv.w;
      o[1][0] += pv.y*vv.x; o[1][1] += pv.y*vv.y; o[1][2] += pv.y*vv.z; o[1][3] += pv.y*vv.w;
      o[2][0] += pv.z*vv.x; o[2][1] += pv.z*vv.y; o[2][2] += pv.z*vv.z; o[2][3] += pv.z*vv.w;
      o[3][0] += pv.w*vv.x; o[3][1] += pv.w*vv.y; o[3][2] += pv.w*vv.z; o[3][3] += pv.w*vv.w;
    }
  }

  const int b = bh / H_, h = bh - (bh / H_) * H_;
#pragma unroll
  for (int i=0;i<4;i++){
    const float inv = 1.0f / li[i];
    const int q = q0 + ty*4 + i;
#pragma unroll
    for (int j=0;j<4;j++)
      ctx[((size_t)(b*S_ + q))*D_ + h*DH_ + tx*4 + j] = f2b(o[i][j] * inv);
  }
}

// ---------------- layernorm over D=768 (3 elems/thread @ 256 threads) ----------------
template<typename T> __device__ __forceinline__ void stf(T* p, float v);
template<> __device__ __forceinline__ void stf<float>(float* p, float v){ *p = v; }
template<> __device__ __forceinline__ void stf<bf16>(bf16* p, float v){ *p = f2b(v); }

template<typename OutT>
__global__ __launch_bounds__(256) void layernorm_k(const bf16* __restrict__ X,
    const float* __restrict__ g, const float* __restrict__ bta, OutT* __restrict__ Y)
{
  const int row = blockIdx.x;
  const int tid = threadIdx.x;
  const bf16* xr = X + (size_t)row * D_;
  float vals[3];
  float s = 0.f, s2 = 0.f;
#pragma unroll
  for (int i = 0; i < 3; i++){
    float v = b2f(xr[tid + i*256]);
    vals[i] = v; s += v; s2 += v*v;
  }
#pragma unroll
  for (int o = 32; o > 0; o >>= 1){ s += __shfl_down(s, o); s2 += __shfl_down(s2, o); }
  __shared__ float rs[4], rq[4];
  const int lane = tid & 63, w = tid >> 6;
  if (lane == 0){ rs[w] = s; rq[w] = s2; }
  __syncthreads();
  s  = rs[0]+rs[1]+rs[2]+rs[3];
  s2 = rq[0]+rq[1]+rq[2]+rq[3];
  const float mean = s * (1.0f/D_);
  const float var  = s2 * (1.0f/D_) - mean*mean;
  const float inv  = rsqrtf(var + 1e-5f);
#pragma unroll
  for (int i = 0; i < 3; i++){
    int c = tid + i*256;
    float o = (vals[i] - mean) * inv * g[c] + bta[c];
    stf(Y + (size_t)row*D_ + c, o);
  }
}

extern "C" void kernel_launch(void* const* d_in, const int* in_sizes, int n_in,
                              void* d_out, int out_size, void* d_ws, size_t ws_size,
                              hipStream_t stream)
{
  const float* x   = (const float*)d_in[0];
  const float* Wq  = (const float*)d_in[1];
  const float* bq  = (const float*)d_in[2];
  const float* Wk  = (const float*)d_in[3];
  const float* bk  = (const float*)d_in[4];
  const float* Wv  = (const float*)d_in[5];
  const float* bv  = (const float*)d_in[6];
  const float* Wo  = (const float*)d_in[7];
  const float* bo  = (const float*)d_in[8];
  const float* W1  = (const float*)d_in[9];
  const float* b1  = (const float*)d_in[10];
  const float* W2  = (const float*)d_in[11];
  const float* b2  = (const float*)d_in[12];
  const float* g1  = (const float*)d_in[13];
  const float* be1 = (const float*)d_in[14];
  const float* g2  = (const float*)d_in[15];
  const float* be2 = (const float*)d_in[16];
  float* out = (float*)d_out;

  char* ws = (char*)d_ws;
  size_t off = 0;
  auto alloc = [&](size_t bytes)->char*{
    char* p = ws + off; off = (off + bytes + 255) & ~(size_t)255; return p;
  };
  bf16*  xb    = (bf16*) alloc((size_t)NTOK*D_*2);     // A for QKV + residual
  bf16*  WcatT = (bf16*) alloc((size_t)3*D_*D_*2);     // [2304][768]
  float* bcat  = (float*)alloc((size_t)3*D_*4);
  bf16*  WoT   = (bf16*) alloc((size_t)D_*D_*2);       // [768][768]
  bf16*  W1T   = (bf16*) alloc((size_t)F_*D_*2);       // [3072][768]
  bf16*  W2T   = (bf16*) alloc((size_t)D_*F_*2);       // [768][3072]
  bf16*  r1    = (bf16*) alloc((size_t)NTOK*F_*2);     // qkv then ff1
  bf16*  qb    = r1;
  bf16*  kb    = r1 + (size_t)NTOK*D_;
  bf16*  vb    = r1 + (size_t)2*NTOK*D_;
  bf16*  ff1   = r1;
  bf16*  ctxb  = (bf16*) alloc((size_t)NTOK*D_*2);     // ctx then y2
  bf16*  y1    = (bf16*) alloc((size_t)NTOK*D_*2);
  bf16*  hb    = (bf16*) alloc((size_t)NTOK*D_*2);
  bf16*  y2    = ctxb;

  // converts + transposes + pack
  f32_to_bf16_k<<<(NTOK*D_+255)/256, 256, 0, stream>>>(x, xb, NTOK*D_);
  transpose_f32_bf16_k<<<dim3(D_/32, D_/32), 256, 0, stream>>>(Wo, WoT, D_, D_);
  transpose_f32_bf16_k<<<dim3(F_/32, D_/32), 256, 0, stream>>>(W1, W1T, D_, F_);
  transpose_f32_bf16_k<<<dim3(D_/32, F_/32), 256, 0, stream>>>(W2, W2T, F_, D_);
  pack_qkv_t_k<<<(3*D_*D_+255)/256, 256, 0, stream>>>(Wq,bq,Wk,bk,Wv,bv,WcatT,bcat);

  // 1) fused QKV projection: [8192,768] @ [768,2304] -> scatter q/k/v
  mgemm_k<0><<<dim3(3*D_/128, NTOK/128), 256, 0, stream>>>(
      xb, WcatT, bcat, nullptr, nullptr, NTOK, 3*D_, D_, qb, kb, vb);

  // 2) causal flash attention -> ctx [8192,768]
  fattn_k<<<dim3(BH_, S_/64), 256, 0, stream>>>(qb, kb, vb, ctxb);

  // 3) out-proj + residual: y1 = ctx@Wo + bo + x
  mgemm_k<1><<<dim3(D_/128, NTOK/128), 256, 0, stream>>>(
      ctxb, WoT, bo, xb, y1, NTOK, D_, D_, nullptr, nullptr, nullptr);

  // 4) LN1 -> h
  layernorm_k<bf16><<<NTOK, 256, 0, stream>>>(y1, g1, be1, hb);

  // 5) FF1 + exact GELU
  mgemm_k<2><<<dim3(F_/128, NTOK/128), 256, 0, stream>>>(
      hb, W1T, b1, nullptr, ff1, NTOK, F_, D_, nullptr, nullptr, nullptr);

  // 6) FF2 + residual: y2 = ff1@W2 + b2 + h
  mgemm_k<1><<<dim3(D_/128, NTOK/128), 256, 0, stream>>>(
      ff1, W2T, b2, hb, y2, NTOK, D_, F_, nullptr, nullptr, nullptr);

  // 7) LN2 -> out (fp32)
  layernorm_k<float><<<NTOK, 256, 0, stream>>>(y2, g2, be2, out);
}

// Round 3
// 466.859 us; speedup vs baseline: 11.7725x; 1.8315x over previous
//
#include <hip/hip_runtime.h>
#include <hip/hip_bf16.h>
#include <math.h>

#define B_ 4
#define S_ 2048
#define D_ 768
#define H_ 12
#define DH_ 64
#define F_ 3072
#define NTOK (B_*S_)   // 8192
#define BH_ (B_*H_)    // 48

typedef __hip_bfloat16 bf16;
typedef __attribute__((ext_vector_type(8))) short bf16x8;   // 8 bf16 = 4 VGPRs (MFMA A/B frag)
typedef __attribute__((ext_vector_type(4))) float f32x4;    // MFMA C/D frag
typedef __attribute__((ext_vector_type(4))) _Float16 half4;
typedef __attribute__((ext_vector_type(8))) _Float16 half8;

__device__ __forceinline__ float bs2f(short s){
  union { unsigned int u; float f; } cv; cv.u = ((unsigned int)(unsigned short)s) << 16; return cv.f;
}
__device__ __forceinline__ float b2f(bf16 v){ return __bfloat162float(v); }
__device__ __forceinline__ bf16 f2b(float v){ return __float2bfloat16(v); }
__device__ __forceinline__ short f2bb(float v){ bf16 b = f2b(v); short s; __builtin_memcpy(&s, &b, 2); return s; }

// ---------------- fp32 -> bf16 convert ----------------
__global__ void f32_to_bf16_k(const float* __restrict__ in, bf16* __restrict__ out, int n){
  int i = blockIdx.x*256 + threadIdx.x;
  if (i < n) out[i] = f2b(in[i]);
}

// ------- transpose+convert: in[K][N] f32 -> out[N][K] bf16 (LDS 32x32 tiles) -------
__global__ __launch_bounds__(256) void transpose_f32_bf16_k(const float* __restrict__ in,
    bf16* __restrict__ out, int K, int N){
  __shared__ float t[32][33];
  const int kb = blockIdx.y*32, nb = blockIdx.x*32;
  const int x = threadIdx.x & 31, y = threadIdx.x >> 5;
#pragma unroll
  for (int yy = y; yy < 32; yy += 8)
    t[yy][x] = in[(size_t)(kb+yy)*N + nb + x];
  __syncthreads();
#pragma unroll
  for (int yy = y; yy < 32; yy += 8)
    out[(size_t)(nb+yy)*K + kb + x] = f2b(t[x][yy]);
}

// ---- pack Wq/Wk/Wv [H,D,Dh] -> WcatT [3D][D] (n-major, k contiguous), biases -> bcat[3D] ----
__global__ void pack_qkv_t_k(const float* __restrict__ Wq, const float* __restrict__ bq,
                             const float* __restrict__ Wk, const float* __restrict__ bk,
                             const float* __restrict__ Wv, const float* __restrict__ bv,
                             bf16* __restrict__ Wt, float* __restrict__ bcat){
  int idx = blockIdx.x*256 + threadIdx.x;
  if (idx < 3*D_*D_){
    int n = idx / D_;
    int k = idx - n*D_;
    int which = n / D_;
    int cc = n - which*D_;
    int h = cc >> 6, e = cc & 63;
    const float* W = (which==0) ? Wq : ((which==1) ? Wk : Wv);
    Wt[idx] = f2b(W[((size_t)h*D_ + k)*DH_ + e]);
  }
  if (idx < 3*D_){
    int which = idx / D_;
    int cc = idx - which*D_;
    int h = cc >> 6, e = cc & 63;
    const float* bb = (which==0) ? bq : ((which==1) ? bk : bv);
    bcat[idx] = bb[h*DH_ + e];
  }
}

// ---------------- MFMA GEMM: C[M,N] = A[M,K] @ Bt[N,K]^T  (+bias, epilogues) ----------------
// EPI 0: +bias; q part scaled 1/8 -> qb[bh][s][e]; k -> kb; v -> f16 vt[bh][e][s'] (key-permuted)
// EPI 1: +bias+aux residual -> bf16 C ;  EPI 2: +bias, exact GELU -> bf16 C
template<int EPI>
__global__ __launch_bounds__(256) void mgemm_k(
    const bf16* __restrict__ A, const bf16* __restrict__ Bt,
    const float* __restrict__ bias, const bf16* __restrict__ aux,
    bf16* __restrict__ C, int M, int N, int K,
    bf16* __restrict__ qb, bf16* __restrict__ kbuf, _Float16* __restrict__ vt)
{
  __shared__ bf16 As[128][40];
  __shared__ bf16 Bs[128][40];
  const int tid  = threadIdx.x;
  const int wave = tid >> 6, lane = tid & 63;
  const int quad = lane >> 4, l16 = lane & 15;
  const int wm = (wave >> 1) * 64, wn = (wave & 1) * 64;
  const int m0 = blockIdx.y * 128, n0 = blockIdx.x * 128;
  const int sr = tid >> 2;
  const int sc = (tid & 3) * 8;

  f32x4 acc[4][4];
#pragma unroll
  for (int i=0;i<4;i++)
#pragma unroll
    for (int j=0;j<4;j++) acc[i][j] = (f32x4)0.f;

  for (int k0 = 0; k0 < K; k0 += 32){
    __syncthreads();
    *(bf16x8*)&As[sr     ][sc] = *(const bf16x8*)(A  + (size_t)(m0+sr   )*K + k0 + sc);
    *(bf16x8*)&As[sr + 64][sc] = *(const bf16x8*)(A  + (size_t)(m0+sr+64)*K + k0 + sc);
    *(bf16x8*)&Bs[sr     ][sc] = *(const bf16x8*)(Bt + (size_t)(n0+sr   )*K + k0 + sc);
    *(bf16x8*)&Bs[sr + 64][sc] = *(const bf16x8*)(Bt + (size_t)(n0+sr+64)*K + k0 + sc);
    __syncthreads();
    bf16x8 af[4], bfr[4];
#pragma unroll
    for (int i=0;i<4;i++) af[i]  = *(const bf16x8*)&As[wm + i*16 + l16][quad*8];
#pragma unroll
    for (int j=0;j<4;j++) bfr[j] = *(const bf16x8*)&Bs[wn + j*16 + l16][quad*8];
#pragma unroll
    for (int i=0;i<4;i++)
#pragma unroll
      for (int j=0;j<4;j++)
        acc[i][j] = __builtin_amdgcn_mfma_f32_16x16x32_bf16(af[i], bfr[j], acc[i][j], 0, 0, 0);
  }

#pragma unroll
  for (int i=0;i<4;i++){
#pragma unroll
    for (int j=0;j<4;j++){
      const int n = n0 + wn + j*16 + l16;
      const int m_base = m0 + wm + i*16 + quad*4;
      if (EPI == 0){
        const int which = n / D_;
        const int cc = n - which*D_;
        const int h = cc >> 6, e = cc & 63;
        if (which == 2){
          const int b = m_base >> 11, s = m_base & (S_-1);
          const int sl = s & 63;
          const int perm = ((sl>>2)&3)*16 + ((sl>>4)&3)*4;   // key-permuted V^T layout
          half4 hv;
#pragma unroll
          for (int r=0;r<4;r++) hv[r] = (_Float16)(acc[i][j][r] + bias[n]);
          *(half4*)(vt + ((size_t)(b*H_+h)*DH_ + e)*S_ + (s & ~63) + perm) = hv;
        } else {
          bf16* dst = (which==0) ? qb : kbuf;
          const float sc2 = (which==0) ? 0.125f : 1.0f;   // fold softmax 1/sqrt(64) into q
#pragma unroll
          for (int r=0;r<4;r++){
            const int m = m_base + r;
            const int b = m >> 11, s = m & (S_-1);
            dst[((size_t)(b*H_+h)*S_ + s)*DH_ + e] = f2b((acc[i][j][r] + bias[n]) * sc2);
          }
        }
      } else {
#pragma unroll
        for (int r=0;r<4;r++){
          const int m = m_base + r;
          float v = acc[i][j][r] + bias[n];
          if (EPI == 1){
            v += b2f(aux[(size_t)m*N + n]);
            C[(size_t)m*N + n] = f2b(v);
          } else {
            v = 0.5f * v * (1.0f + erff(v * 0.70710678118654752f));
            C[(size_t)m*N + n] = f2b(v);
          }
        }
      }
    }
  }
}

// ---------------- MFMA flash attention ----------------
// Block: 64 queries (q0..q0+63), 4 waves in 2x2 (kh = key-half, qh = query-half).
// S^T = K@Q^T via 16x16x32_bf16 (A=K rows, B=Q rows); C layout: key=quad*4+r, query=l16.
// PV: O^T += V^T @ P^T via 16x16x16_f16 — S^T's C-frag IS the x16 B-frag (k=quad*4+j, n=l16),
// so P stays in registers. V^T staged from the pre-transposed, key-permuted global vt buffer.
__global__ __launch_bounds__(256) void fattn_k(const bf16* __restrict__ qb,
    const bf16* __restrict__ kb, const _Float16* __restrict__ vt, bf16* __restrict__ ctx)
{
  __shared__ __align__(16) char smem[19456];
  bf16     (*Ks)[72] = (bf16(*)[72])smem;                  // [64 keys][72] bf16, 9216 B
  _Float16 (*Vs)[72] = (_Float16(*)[72])(smem + 9216);     // [64 d][72 keys(permuted)] f16
  float* maxb  = (float*)(smem + 18432);                   // [2 kh][64 q]
  float* libuf = (float*)(smem + 18944);                   // [2 kh][64 q]
  float* Obuf  = (float*)smem;                             // alias (end): [(qh*64+d)*33 + q32]

  const int bh = blockIdx.x;
  const int qt = 31 - blockIdx.y;       // heavy tiles first
  const int q0 = qt * 64;
  const int tid = threadIdx.x;
  const int wave = tid >> 6, lane = tid & 63;
  const int quad = lane >> 4, l16 = lane & 15;
  const int kh = wave >> 1, qh = wave & 1;
  const size_t kbase = (size_t)bh * S_ * DH_;

  // Q B-frags (loop-invariant): qf[nf][h] = Q[q0+qh*32+nf*16+l16][h*32+quad*8 ..+7]
  bf16x8 qf[2][2];
#pragma unroll
  for (int nf=0; nf<2; nf++)
#pragma unroll
    for (int h=0; h<2; h++)
      qf[nf][h] = *(const bf16x8*)(qb + kbase + (size_t)(q0 + qh*32 + nf*16 + l16)*DH_ + h*32 + quad*8);

  f32x4 o[4][2];
#pragma unroll
  for (int df=0; df<4; df++){ o[df][0] = (f32x4)0.f; o[df][1] = (f32x4)0.f; }
  float mi[2] = {-1e30f, -1e30f}, li[2] = {0.f, 0.f};

  for (int kt = 0; kt <= qt; ++kt){
    const int k0 = kt * 64;
    __syncthreads();                               // prior-iter frag reads + maxb reads done
    { // stage K (bf16, natural order) and V^T (f16, permuted keys)
      const int r = tid >> 2, seg = (tid & 3) * 16;
      const bf16* ksrc = kb + kbase + (size_t)(k0 + r)*DH_ + seg;
      bf16x8 ka = *(const bf16x8*)ksrc;
      bf16x8 kc2 = *(const bf16x8*)(ksrc + 8);
      *(bf16x8*)&Ks[r][seg]   = ka;
      *(bf16x8*)&Ks[r][seg+8] = kc2;
      const _Float16* vsrc = vt + ((size_t)bh*DH_ + r)*S_ + k0 + seg;
      half8 va = *(const half8*)vsrc;
      half8 vb2 = *(const half8*)(vsrc + 8);
      *(half8*)&Vs[r][seg]   = va;
      *(half8*)&Vs[r][seg+8] = vb2;
    }
    __syncthreads();

    // S^T: sc[mf][nf], keys kh*32+mf*16+quad*4+r, queries qh*32+nf*16+l16
    bf16x8 af[2][2];
#pragma unroll
    for (int mf=0; mf<2; mf++)
#pragma unroll
      for (int h=0; h<2; h++)
        af[mf][h] = *(const bf16x8*)&Ks[kh*32 + mf*16 + l16][h*32 + quad*8];
    f32x4 sc[2][2];
#pragma unroll
    for (int mf=0; mf<2; mf++)
#pragma unroll
      for (int nf=0; nf<2; nf++){
        f32x4 t = __builtin_amdgcn_mfma_f32_16x16x32_bf16(af[mf][0], qf[nf][0], (f32x4)0.f, 0, 0, 0);
        sc[mf][nf] = __builtin_amdgcn_mfma_f32_16x16x32_bf16(af[mf][1], qf[nf][1], t, 0, 0, 0);
      }

    if (kt == qt){ // diagonal tile: causal mask (local key > local query)
#pragma unroll
      for (int mf=0; mf<2; mf++){
        const int keyl = kh*32 + mf*16 + quad*4;
#pragma unroll
        for (int nf=0; nf<2; nf++){
          const int ql = qh*32 + nf*16 + l16;
#pragma unroll
          for (int r=0; r<4; r++)
            if (keyl + r > ql) sc[mf][nf][r] = -1e30f;
        }
      }
    }

    // wave-partial row max (over this wave's 32 keys) per query
    float mw[2];
#pragma unroll
    for (int nf=0; nf<2; nf++){
      float mx = -1e30f;
#pragma unroll
      for (int mf=0; mf<2; mf++)
#pragma unroll
        for (int r=0; r<4; r++) mx = fmaxf(mx, sc[mf][nf][r]);
      mx = fmaxf(mx, __shfl_xor(mx, 16));
      mx = fmaxf(mx, __shfl_xor(mx, 32));
      mw[nf] = mx;
    }
    if (quad == 0){
      maxb[kh*64 + qh*32 + l16]      = mw[0];
      maxb[kh*64 + qh*32 + 16 + l16] = mw[1];
    }
    __syncthreads();

    half4 pf[2][2];
    float alpha[2];
#pragma unroll
    for (int nf=0; nf<2; nf++){
      const float mo = maxb[(1-kh)*64 + qh*32 + nf*16 + l16];
      const float mn = fmaxf(mi[nf], fmaxf(mw[nf], mo));
      alpha[nf] = __expf(mi[nf] - mn);
      mi[nf] = mn;
      float rs = 0.f;
#pragma unroll
      for (int mf=0; mf<2; mf++)
#pragma unroll
        for (int r=0; r<4; r++){
          float p = __expf(sc[mf][nf][r] - mn);
          pf[mf][nf][r] = (_Float16)p;
          rs += p;
        }
      rs += __shfl_xor(rs, 16);
      rs += __shfl_xor(rs, 32);
      li[nf] = li[nf]*alpha[nf] + rs;
    }

    // rescale O, then PV
#pragma unroll
    for (int df=0; df<4; df++)
#pragma unroll
      for (int nf=0; nf<2; nf++)
#pragma unroll
        for (int r=0; r<4; r++) o[df][nf][r] *= alpha[nf];

#pragma unroll
    for (int df=0; df<4; df++){
      half8 vv = *(const half8*)&Vs[df*16 + l16][quad*16 + kh*8];   // keys mf=0 (lo4), mf=1 (hi4)
      half4 vlo = __builtin_shufflevector(vv, vv, 0,1,2,3);
      half4 vhi = __builtin_shufflevector(vv, vv, 4,5,6,7);
#pragma unroll
      for (int nf=0; nf<2; nf++){
        o[df][nf] = __builtin_amdgcn_mfma_f32_16x16x16f16(vlo, pf[0][nf], o[df][nf], 0, 0, 0);
        o[df][nf] = __builtin_amdgcn_mfma_f32_16x16x16f16(vhi, pf[1][nf], o[df][nf], 0, 0, 0);
      }
    }
  }

  // ---- cross-wave merge (kh=1 partials into kh=0) + epilogue ----
  __syncthreads();
  if (quad == 0){
    libuf[kh*64 + qh*32 + l16]      = li[0];
    libuf[kh*64 + qh*32 + 16 + l16] = li[1];
  }
  if (kh == 1){
#pragma unroll
    for (int df=0; df<4; df++)
#pragma unroll
      for (int nf=0; nf<2; nf++)
#pragma unroll
        for (int r=0; r<4; r++)
          Obuf[(qh*64 + df*16 + quad*4 + r)*33 + nf*16 + l16] = o[df][nf][r];
  }
  __syncthreads();
  if (kh == 0){
    const int b = bh / H_, h = bh - (bh / H_)*H_;
#pragma unroll
    for (int nf=0; nf<2; nf++){
      const int q64 = qh*32 + nf*16 + l16;
      const float inv = 1.0f / (libuf[q64] + libuf[64 + q64]);
      const int qtok = q0 + q64;
#pragma unroll
      for (int df=0; df<4; df++){
        short4 pk;
        float v0 = (o[df][nf][0] + Obuf[(qh*64 + df*16 + quad*4 + 0)*33 + nf*16 + l16]) * inv;
        float v1 = (o[df][nf][1] + Obuf[(qh*64 + df*16 + quad*4 + 1)*33 + nf*16 + l16]) * inv;
        float v2 = (o[df][nf][2] + Obuf[(qh*64 + df*16 + quad*4 + 2)*33 + nf*16 + l16]) * inv;
        float v3 = (o[df][nf][3] + Obuf[(qh*64 + df*16 + quad*4 + 3)*33 + nf*16 + l16]) * inv;
        pk.x = f2bb(v0); pk.y = f2bb(v1); pk.z = f2bb(v2); pk.w = f2bb(v3);
        *(short4*)((short*)ctx + ((size_t)(b*S_ + qtok))*D_ + h*DH_ + df*16 + quad*4) = pk;
      }
    }
  }
}

// ---------------- layernorm over D=768 (3 elems/thread @ 256 threads) ----------------
template<typename T> __device__ __forceinline__ void stf(T* p, float v);
template<> __device__ __forceinline__ void stf<float>(float* p, float v){ *p = v; }
template<> __device__ __forceinline__ void stf<bf16>(bf16* p, float v){ *p = f2b(v); }

template<typename OutT>
__global__ __launch_bounds__(256) void layernorm_k(const bf16* __restrict__ X,
    const float* __restrict__ g, const float* __restrict__ bta, OutT* __restrict__ Y)
{
  const int row = blockIdx.x;
  const int tid = threadIdx.x;
  const bf16* xr = X + (size_t)row * D_;
  float vals[3];
  float s = 0.f, s2 = 0.f;
#pragma unroll
  for (int i = 0; i < 3; i++){
    float v = b2f(xr[tid + i*256]);
    vals[i] = v; s += v; s2 += v*v;
  }
#pragma unroll
  for (int o = 32; o > 0; o >>= 1){ s += __shfl_down(s, o); s2 += __shfl_down(s2, o); }
  __shared__ float rs[4], rq[4];
  const int lane = tid & 63, w = tid >> 6;
  if (lane == 0){ rs[w] = s; rq[w] = s2; }
  __syncthreads();
  s  = rs[0]+rs[1]+rs[2]+rs[3];
  s2 = rq[0]+rq[1]+rq[2]+rq[3];
  const float mean = s * (1.0f/D_);
  const float var  = s2 * (1.0f/D_) - mean*mean;
  const float inv  = rsqrtf(var + 1e-5f);
#pragma unroll
  for (int i = 0; i < 3; i++){
    int c = tid + i*256;
    float o = (vals[i] - mean) * inv * g[c] + bta[c];
    stf(Y + (size_t)row*D_ + c, o);
  }
}

extern "C" void kernel_launch(void* const* d_in, const int* in_sizes, int n_in,
                              void* d_out, int out_size, void* d_ws, size_t ws_size,
                              hipStream_t stream)
{
  const float* x   = (const float*)d_in[0];
  const float* Wq  = (const float*)d_in[1];
  const float* bq  = (const float*)d_in[2];
  const float* Wk  = (const float*)d_in[3];
  const float* bk  = (const float*)d_in[4];
  const float* Wv  = (const float*)d_in[5];
  const float* bv  = (const float*)d_in[6];
  const float* Wo  = (const float*)d_in[7];
  const float* bo  = (const float*)d_in[8];
  const float* W1  = (const float*)d_in[9];
  const float* b1  = (const float*)d_in[10];
  const float* W2  = (const float*)d_in[11];
  const float* b2  = (const float*)d_in[12];
  const float* g1  = (const float*)d_in[13];
  const float* be1 = (const float*)d_in[14];
  const float* g2  = (const float*)d_in[15];
  const float* be2 = (const float*)d_in[16];
  float* out = (float*)d_out;

  char* ws = (char*)d_ws;
  size_t off = 0;
  auto alloc = [&](size_t bytes)->char*{
    char* p = ws + off; off = (off + bytes + 255) & ~(size_t)255; return p;
  };
  bf16*  xb    = (bf16*) alloc((size_t)NTOK*D_*2);
  bf16*  WcatT = (bf16*) alloc((size_t)3*D_*D_*2);
  float* bcat  = (float*)alloc((size_t)3*D_*4);
  bf16*  WoT   = (bf16*) alloc((size_t)D_*D_*2);
  bf16*  W1T   = (bf16*) alloc((size_t)F_*D_*2);
  bf16*  W2T   = (bf16*) alloc((size_t)D_*F_*2);
  bf16*  r1    = (bf16*) alloc((size_t)NTOK*F_*2);     // q,k,vt then ff1
  bf16*  qb    = r1;
  bf16*  kb    = r1 + (size_t)NTOK*D_;
  _Float16* vt = (_Float16*)(r1 + (size_t)2*NTOK*D_);  // [bh*64+d][S], f16, key-permuted
  bf16*  ff1   = r1;
  bf16*  ctxb  = (bf16*) alloc((size_t)NTOK*D_*2);     // ctx then y2
  bf16*  y1    = (bf16*) alloc((size_t)NTOK*D_*2);
  bf16*  hb    = (bf16*) alloc((size_t)NTOK*D_*2);
  bf16*  y2    = ctxb;

  f32_to_bf16_k<<<(NTOK*D_+255)/256, 256, 0, stream>>>(x, xb, NTOK*D_);
  transpose_f32_bf16_k<<<dim3(D_/32, D_/32), 256, 0, stream>>>(Wo, WoT, D_, D_);
  transpose_f32_bf16_k<<<dim3(F_/32, D_/32), 256, 0, stream>>>(W1, W1T, D_, F_);
  transpose_f32_bf16_k<<<dim3(D_/32, F_/32), 256, 0, stream>>>(W2, W2T, F_, D_);
  pack_qkv_t_k<<<(3*D_*D_+255)/256, 256, 0, stream>>>(Wq,bq,Wk,bk,Wv,bv,WcatT,bcat);

  // 1) fused QKV projection (q pre-scaled 1/8; v written transposed+permuted f16)
  mgemm_k<0><<<dim3(3*D_/128, NTOK/128), 256, 0, stream>>>(
      xb, WcatT, bcat, nullptr, nullptr, NTOK, 3*D_, D_, qb, kb, vt);

  // 2) MFMA flash attention -> ctx [8192,768]
  fattn_k<<<dim3(BH_, S_/64), 256, 0, stream>>>(qb, kb, vt, ctxb);

  // 3) out-proj + residual: y1 = ctx@Wo + bo + x
  mgemm_k<1><<<dim3(D_/128, NTOK/128), 256, 0, stream>>>(
      ctxb, WoT, bo, xb, y1, NTOK, D_, D_, nullptr, nullptr, nullptr);

  // 4) LN1 -> h
  layernorm_k<bf16><<<NTOK, 256, 0, stream>>>(y1, g1, be1, hb);

  // 5) FF1 + exact GELU
  mgemm_k<2><<<dim3(F_/128, NTOK/128), 256, 0, stream>>>(
      hb, W1T, b1, nullptr, ff1, NTOK, F_, D_, nullptr, nullptr, nullptr);

  // 6) FF2 + residual: y2 = ff1@W2 + b2 + h
  mgemm_k<1><<<dim3(D_/128, NTOK/128), 256, 0, stream>>>(
      ff1, W2T, b2, hb, y2, NTOK, D_, F_, nullptr, nullptr, nullptr);

  // 7) LN2 -> out (fp32)
  layernorm_k<float><<<NTOK, 256, 0, stream>>>(y2, g2, be2, out);
}

// Round 4
// 451.770 us; speedup vs baseline: 12.1657x; 1.0334x over previous
//
#include <hip/hip_runtime.h>
#include <hip/hip_bf16.h>
#include <math.h>

#define B_ 4
#define S_ 2048
#define D_ 768
#define H_ 12
#define DH_ 64
#define F_ 3072
#define NTOK (B_*S_)   // 8192
#define BH_ (B_*H_)    // 48

typedef __hip_bfloat16 bf16;
typedef __attribute__((ext_vector_type(8))) short bf16x8;   // 8 bf16 = 4 VGPRs (MFMA A/B frag)
typedef __attribute__((ext_vector_type(4))) float f32x4;    // MFMA C/D frag
typedef __attribute__((ext_vector_type(4))) _Float16 half4;
typedef __attribute__((ext_vector_type(8))) _Float16 half8;

// async global->LDS: 16 B/lane, lane i lands at ldsbase + i*16 (wave-uniform base)
#define GLD16(g, l) __builtin_amdgcn_global_load_lds( \
    (__attribute__((address_space(1))) void*)(uintptr_t)(g), \
    (__attribute__((address_space(3))) void*)(uintptr_t)(l), 16, 0, 0)

__device__ __forceinline__ float bs2f(short s){
  union { unsigned int u; float f; } cv; cv.u = ((unsigned int)(unsigned short)s) << 16; return cv.f;
}
__device__ __forceinline__ float b2f(bf16 v){ return __bfloat162float(v); }
__device__ __forceinline__ bf16 f2b(float v){ return __float2bfloat16(v); }
__device__ __forceinline__ short f2bb(float v){ bf16 b = f2b(v); short s; __builtin_memcpy(&s, &b, 2); return s; }

// ---------------- fp32 -> bf16 convert ----------------
__global__ void f32_to_bf16_k(const float* __restrict__ in, bf16* __restrict__ out, int n){
  int i = blockIdx.x*256 + threadIdx.x;
  if (i < n) out[i] = f2b(in[i]);
}

// ------- transpose+convert: in[K][N] f32 -> out[N][K] bf16 (LDS 32x32 tiles) -------
__global__ __launch_bounds__(256) void transpose_f32_bf16_k(const float* __restrict__ in,
    bf16* __restrict__ out, int K, int N){
  __shared__ float t[32][33];
  const int kb = blockIdx.y*32, nb = blockIdx.x*32;
  const int x = threadIdx.x & 31, y = threadIdx.x >> 5;
#pragma unroll
  for (int yy = y; yy < 32; yy += 8)
    t[yy][x] = in[(size_t)(kb+yy)*N + nb + x];
  __syncthreads();
#pragma unroll
  for (int yy = y; yy < 32; yy += 8)
    out[(size_t)(nb+yy)*K + kb + x] = f2b(t[x][yy]);
}

// ---- pack Wq/Wk/Wv [H,D,Dh] -> WcatT [3D][D] (n-major, k contiguous), biases -> bcat[3D] ----
__global__ void pack_qkv_t_k(const float* __restrict__ Wq, const float* __restrict__ bq,
                             const float* __restrict__ Wk, const float* __restrict__ bk,
                             const float* __restrict__ Wv, const float* __restrict__ bv,
                             bf16* __restrict__ Wt, float* __restrict__ bcat){
  int idx = blockIdx.x*256 + threadIdx.x;
  if (idx < 3*D_*D_){
    int n = idx / D_;
    int k = idx - n*D_;
    int which = n / D_;
    int cc = n - which*D_;
    int h = cc >> 6, e = cc & 63;
    const float* W = (which==0) ? Wq : ((which==1) ? Wk : Wv);
    Wt[idx] = f2b(W[((size_t)h*D_ + k)*DH_ + e]);
  }
  if (idx < 3*D_){
    int which = idx / D_;
    int cc = idx - which*D_;
    int h = cc >> 6, e = cc & 63;
    const float* bb = (which==0) ? bq : ((which==1) ? bk : bv);
    bcat[idx] = bb[h*DH_ + e];
  }
}

// ---------------- MFMA GEMM: C[M,N] = A[M,K] @ Bt[N,K]^T  (+bias, epilogues) ----------------
// m97 structure: 128x128 tile, BK=32, 4 waves 2x2 (64x64 each), global_load_lds width-16
// staging into unpadded [128][32] LDS with XOR chunk swizzle (chunk c of row r at slot c^(r&3)).
// EPI 0: +bias; q scaled 1/8 -> qb; k -> kb; v -> f16 vt[bh][e][s'] (key-permuted)
// EPI 1: +bias+aux residual -> bf16 C ;  EPI 2: +bias, exact GELU -> bf16 C
template<int EPI>
__global__ __launch_bounds__(256) void mgemm_k(
    const bf16* __restrict__ A, const bf16* __restrict__ Bt,
    const float* __restrict__ bias, const bf16* __restrict__ aux,
    bf16* __restrict__ C, int M, int N, int K,
    bf16* __restrict__ qb, bf16* __restrict__ kbuf, _Float16* __restrict__ vt)
{
  __shared__ bf16 As[4096];   // [128][32] unpadded, 8 KB
  __shared__ bf16 Bs[4096];
  const int tid  = threadIdx.x;
  const int wave = tid >> 6, lane = tid & 63;
  const int quad = lane >> 4, l16 = lane & 15;
  const int wm = (wave >> 1) * 64, wn = (wave & 1) * 64;
  const int m0 = blockIdx.y * 128, n0 = blockIdx.x * 128;

  // staging: lane covers row wave*16 + (lane>>2), swizzled chunk ((lane&3)^(row&3))
  const int srow  = lane >> 2;
  const int schunk = (lane & 3) ^ (srow & 3);
  const bf16* gA0 = A  + (size_t)(m0 + wave*16 + srow)*K + schunk*8;
  const bf16* gA1 = gA0 + (size_t)64*K;
  const bf16* gB0 = Bt + (size_t)(n0 + wave*16 + srow)*K + schunk*8;
  const bf16* gB1 = gB0 + (size_t)64*K;
  const uintptr_t asb = (uintptr_t)(void*)As + (size_t)wave*1024;
  const uintptr_t bsb = (uintptr_t)(void*)Bs + (size_t)wave*1024;

  f32x4 acc[4][4];
#pragma unroll
  for (int i=0;i<4;i++)
#pragma unroll
    for (int j=0;j<4;j++) acc[i][j] = (f32x4)0.f;

  const char* AsB = (const char*)As;
  const char* BsB = (const char*)Bs;
  const int fsw = (quad ^ (l16 & 3)) * 16;   // frag-read swizzled chunk byte offset

  for (int k0 = 0; k0 < K; k0 += 32){
    __syncthreads();                      // prior frag reads done before overwrite
    GLD16(gA0, asb);
    GLD16(gA1, asb + 4096);
    GLD16(gB0, bsb);
    GLD16(gB1, bsb + 4096);
    gA0 += 32; gA1 += 32; gB0 += 32; gB1 += 32;
    __syncthreads();                      // drains vmcnt -> LDS visible
    bf16x8 af[4], bfr[4];
#pragma unroll
    for (int i=0;i<4;i++) af[i]  = *(const bf16x8*)(AsB + ((wm + i*16 + l16) << 6) + fsw);
#pragma unroll
    for (int j=0;j<4;j++) bfr[j] = *(const bf16x8*)(BsB + ((wn + j*16 + l16) << 6) + fsw);
#pragma unroll
    for (int i=0;i<4;i++)
#pragma unroll
      for (int j=0;j<4;j++)
        acc[i][j] = __builtin_amdgcn_mfma_f32_16x16x32_bf16(af[i], bfr[j], acc[i][j], 0, 0, 0);
  }

#pragma unroll
  for (int i=0;i<4;i++){
#pragma unroll
    for (int j=0;j<4;j++){
      const int n = n0 + wn + j*16 + l16;
      const int m_base = m0 + wm + i*16 + quad*4;
      if (EPI == 0){
        const int which = n / D_;
        const int cc = n - which*D_;
        const int h = cc >> 6, e = cc & 63;
        if (which == 2){
          const int b = m_base >> 11, s = m_base & (S_-1);
          const int sl = s & 63;
          const int perm = ((sl>>2)&3)*16 + ((sl>>4)&3)*4;   // key-permuted V^T layout
          half4 hv;
#pragma unroll
          for (int r=0;r<4;r++) hv[r] = (_Float16)(acc[i][j][r] + bias[n]);
          *(half4*)(vt + ((size_t)(b*H_+h)*DH_ + e)*S_ + (s & ~63) + perm) = hv;
        } else {
          bf16* dst = (which==0) ? qb : kbuf;
          const float sc2 = (which==0) ? 0.125f : 1.0f;   // fold softmax 1/sqrt(64) into q
#pragma unroll
          for (int r=0;r<4;r++){
            const int m = m_base + r;
            const int b = m >> 11, s = m & (S_-1);
            dst[((size_t)(b*H_+h)*S_ + s)*DH_ + e] = f2b((acc[i][j][r] + bias[n]) * sc2);
          }
        }
      } else {
#pragma unroll
        for (int r=0;r<4;r++){
          const int m = m_base + r;
          float v = acc[i][j][r] + bias[n];
          if (EPI == 1){
            v += b2f(aux[(size_t)m*N + n]);
            C[(size_t)m*N + n] = f2b(v);
          } else {
            v = 0.5f * v * (1.0f + erff(v * 0.70710678118654752f));
            C[(size_t)m*N + n] = f2b(v);
          }
        }
      }
    }
  }
}

// ---------------- MFMA flash attention ----------------
// Block: 64 queries, 4 waves in 2x2 (kh = key-half, qh = query-half).
// S^T = K@Q^T via 16x16x32_bf16; C layout: key=quad*4+r, query=l16.
// PV: O^T += V^T @ P^T via 16x16x16_f16 — S^T's C-frag IS the x16 B-frag, P stays in registers.
__global__ __launch_bounds__(256) void fattn_k(const bf16* __restrict__ qb,
    const bf16* __restrict__ kb, const _Float16* __restrict__ vt, bf16* __restrict__ ctx)
{
  __shared__ __align__(16) char smem[19456];
  bf16     (*Ks)[72] = (bf16(*)[72])smem;                  // [64 keys][72] bf16
  _Float16 (*Vs)[72] = (_Float16(*)[72])(smem + 9216);     // [64 d][72 keys(permuted)] f16
  float* maxb  = (float*)(smem + 18432);                   // [2 kh][64 q]
  float* libuf = (float*)(smem + 18944);                   // [2 kh][64 q]
  float* Obuf  = (float*)smem;                             // alias (end)

  const int bh = blockIdx.x;
  const int qt = 31 - blockIdx.y;       // heavy tiles first
  const int q0 = qt * 64;
  const int tid = threadIdx.x;
  const int wave = tid >> 6, lane = tid & 63;
  const int quad = lane >> 4, l16 = lane & 15;
  const int kh = wave >> 1, qh = wave & 1;
  const size_t kbase = (size_t)bh * S_ * DH_;

  bf16x8 qf[2][2];
#pragma unroll
  for (int nf=0; nf<2; nf++)
#pragma unroll
    for (int h=0; h<2; h++)
      qf[nf][h] = *(const bf16x8*)(qb + kbase + (size_t)(q0 + qh*32 + nf*16 + l16)*DH_ + h*32 + quad*8);

  f32x4 o[4][2];
#pragma unroll
  for (int df=0; df<4; df++){ o[df][0] = (f32x4)0.f; o[df][1] = (f32x4)0.f; }
  float mi[2] = {-1e30f, -1e30f}, li[2] = {0.f, 0.f};

  for (int kt = 0; kt <= qt; ++kt){
    const int k0 = kt * 64;
    __syncthreads();
    { // stage K (natural) and V^T (permuted keys)
      const int r = tid >> 2, seg = (tid & 3) * 16;
      const bf16* ksrc = kb + kbase + (size_t)(k0 + r)*DH_ + seg;
      bf16x8 ka = *(const bf16x8*)ksrc;
      bf16x8 kc2 = *(const bf16x8*)(ksrc + 8);
      *(bf16x8*)&Ks[r][seg]   = ka;
      *(bf16x8*)&Ks[r][seg+8] = kc2;
      const _Float16* vsrc = vt + ((size_t)bh*DH_ + r)*S_ + k0 + seg;
      half8 va = *(const half8*)vsrc;
      half8 vb2 = *(const half8*)(vsrc + 8);
      *(half8*)&Vs[r][seg]   = va;
      *(half8*)&Vs[r][seg+8] = vb2;
    }
    __syncthreads();

    bf16x8 af[2][2];
#pragma unroll
    for (int mf=0; mf<2; mf++)
#pragma unroll
      for (int h=0; h<2; h++)
        af[mf][h] = *(const bf16x8*)&Ks[kh*32 + mf*16 + l16][h*32 + quad*8];
    f32x4 sc[2][2];
#pragma unroll
    for (int mf=0; mf<2; mf++)
#pragma unroll
      for (int nf=0; nf<2; nf++){
        f32x4 t = __builtin_amdgcn_mfma_f32_16x16x32_bf16(af[mf][0], qf[nf][0], (f32x4)0.f, 0, 0, 0);
        sc[mf][nf] = __builtin_amdgcn_mfma_f32_16x16x32_bf16(af[mf][1], qf[nf][1], t, 0, 0, 0);
      }

    if (kt == qt){
#pragma unroll
      for (int mf=0; mf<2; mf++){
        const int keyl = kh*32 + mf*16 + quad*4;
#pragma unroll
        for (int nf=0; nf<2; nf++){
          const int ql = qh*32 + nf*16 + l16;
#pragma unroll
          for (int r=0; r<4; r++)
            if (keyl + r > ql) sc[mf][nf][r] = -1e30f;
        }
      }
    }

    float mw[2];
#pragma unroll
    for (int nf=0; nf<2; nf++){
      float mx = -1e30f;
#pragma unroll
      for (int mf=0; mf<2; mf++)
#pragma unroll
        for (int r=0; r<4; r++) mx = fmaxf(mx, sc[mf][nf][r]);
      mx = fmaxf(mx, __shfl_xor(mx, 16));
      mx = fmaxf(mx, __shfl_xor(mx, 32));
      mw[nf] = mx;
    }
    if (quad == 0){
      maxb[kh*64 + qh*32 + l16]      = mw[0];
      maxb[kh*64 + qh*32 + 16 + l16] = mw[1];
    }
    __syncthreads();

    half4 pf[2][2];
    float alpha[2];
#pragma unroll
    for (int nf=0; nf<2; nf++){
      const float mo = maxb[(1-kh)*64 + qh*32 + nf*16 + l16];
      const float mn = fmaxf(mi[nf], fmaxf(mw[nf], mo));
      alpha[nf] = __expf(mi[nf] - mn);
      mi[nf] = mn;
      float rs = 0.f;
#pragma unroll
      for (int mf=0; mf<2; mf++)
#pragma unroll
        for (int r=0; r<4; r++){
          float p = __expf(sc[mf][nf][r] - mn);
          pf[mf][nf][r] = (_Float16)p;
          rs += p;
        }
      rs += __shfl_xor(rs, 16);
      rs += __shfl_xor(rs, 32);
      li[nf] = li[nf]*alpha[nf] + rs;
    }

#pragma unroll
    for (int df=0; df<4; df++)
#pragma unroll
      for (int nf=0; nf<2; nf++)
#pragma unroll
        for (int r=0; r<4; r++) o[df][nf][r] *= alpha[nf];

#pragma unroll
    for (int df=0; df<4; df++){
      half8 vv = *(const half8*)&Vs[df*16 + l16][quad*16 + kh*8];
      half4 vlo = __builtin_shufflevector(vv, vv, 0,1,2,3);
      half4 vhi = __builtin_shufflevector(vv, vv, 4,5,6,7);
#pragma unroll
      for (int nf=0; nf<2; nf++){
        o[df][nf] = __builtin_amdgcn_mfma_f32_16x16x16f16(vlo, pf[0][nf], o[df][nf], 0, 0, 0);
        o[df][nf] = __builtin_amdgcn_mfma_f32_16x16x16f16(vhi, pf[1][nf], o[df][nf], 0, 0, 0);
      }
    }
  }

  __syncthreads();
  if (quad == 0){
    libuf[kh*64 + qh*32 + l16]      = li[0];
    libuf[kh*64 + qh*32 + 16 + l16] = li[1];
  }
  if (kh == 1){
#pragma unroll
    for (int df=0; df<4; df++)
#pragma unroll
      for (int nf=0; nf<2; nf++)
#pragma unroll
        for (int r=0; r<4; r++)
          Obuf[(qh*64 + df*16 + quad*4 + r)*33 + nf*16 + l16] = o[df][nf][r];
  }
  __syncthreads();
  if (kh == 0){
    const int b = bh / H_, h = bh - (bh / H_)*H_;
#pragma unroll
    for (int nf=0; nf<2; nf++){
      const int q64 = qh*32 + nf*16 + l16;
      const float inv = 1.0f / (libuf[q64] + libuf[64 + q64]);
      const int qtok = q0 + q64;
#pragma unroll
      for (int df=0; df<4; df++){
        short4 pk;
        float v0 = (o[df][nf][0] + Obuf[(qh*64 + df*16 + quad*4 + 0)*33 + nf*16 + l16]) * inv;
        float v1 = (o[df][nf][1] + Obuf[(qh*64 + df*16 + quad*4 + 1)*33 + nf*16 + l16]) * inv;
        float v2 = (o[df][nf][2] + Obuf[(qh*64 + df*16 + quad*4 + 2)*33 + nf*16 + l16]) * inv;
        float v3 = (o[df][nf][3] + Obuf[(qh*64 + df*16 + quad*4 + 3)*33 + nf*16 + l16]) * inv;
        pk.x = f2bb(v0); pk.y = f2bb(v1); pk.z = f2bb(v2); pk.w = f2bb(v3);
        *(short4*)((short*)ctx + ((size_t)(b*S_ + qtok))*D_ + h*DH_ + df*16 + quad*4) = pk;
      }
    }
  }
}

// ---------------- layernorm over D=768 ----------------
template<typename T> __device__ __forceinline__ void stf(T* p, float v);
template<> __device__ __forceinline__ void stf<float>(float* p, float v){ *p = v; }
template<> __device__ __forceinline__ void stf<bf16>(bf16* p, float v){ *p = f2b(v); }

template<typename OutT>
__global__ __launch_bounds__(256) void layernorm_k(const bf16* __restrict__ X,
    const float* __restrict__ g, const float* __restrict__ bta, OutT* __restrict__ Y)
{
  const int row = blockIdx.x;
  const int tid = threadIdx.x;
  const bf16* xr = X + (size_t)row * D_;
  float vals[3];
  float s = 0.f, s2 = 0.f;
#pragma unroll
  for (int i = 0; i < 3; i++){
    float v = b2f(xr[tid + i*256]);
    vals[i] = v; s += v; s2 += v*v;
  }
#pragma unroll
  for (int o = 32; o > 0; o >>= 1){ s += __shfl_down(s, o); s2 += __shfl_down(s2, o); }
  __shared__ float rs[4], rq[4];
  const int lane = tid & 63, w = tid >> 6;
  if (lane == 0){ rs[w] = s; rq[w] = s2; }
  __syncthreads();
  s  = rs[0]+rs[1]+rs[2]+rs[3];
  s2 = rq[0]+rq[1]+rq[2]+rq[3];
  const float mean = s * (1.0f/D_);
  const float var  = s2 * (1.0f/D_) - mean*mean;
  const float inv  = rsqrtf(var + 1e-5f);
#pragma unroll
  for (int i = 0; i < 3; i++){
    int c = tid + i*256;
    float o = (vals[i] - mean) * inv * g[c] + bta[c];
    stf(Y + (size_t)row*D_ + c, o);
  }
}

extern "C" void kernel_launch(void* const* d_in, const int* in_sizes, int n_in,
                              void* d_out, int out_size, void* d_ws, size_t ws_size,
                              hipStream_t stream)
{
  const float* x   = (const float*)d_in[0];
  const float* Wq  = (const float*)d_in[1];
  const float* bq  = (const float*)d_in[2];
  const float* Wk  = (const float*)d_in[3];
  const float* bk  = (const float*)d_in[4];
  const float* Wv  = (const float*)d_in[5];
  const float* bv  = (const float*)d_in[6];
  const float* Wo  = (const float*)d_in[7];
  const float* bo  = (const float*)d_in[8];
  const float* W1  = (const float*)d_in[9];
  const float* b1  = (const float*)d_in[10];
  const float* W2  = (const float*)d_in[11];
  const float* b2  = (const float*)d_in[12];
  const float* g1  = (const float*)d_in[13];
  const float* be1 = (const float*)d_in[14];
  const float* g2  = (const float*)d_in[15];
  const float* be2 = (const float*)d_in[16];
  float* out = (float*)d_out;

  char* ws = (char*)d_ws;
  size_t off = 0;
  auto alloc = [&](size_t bytes)->char*{
    char* p = ws + off; off = (off + bytes + 255) & ~(size_t)255; return p;
  };
  bf16*  xb    = (bf16*) alloc((size_t)NTOK*D_*2);
  bf16*  WcatT = (bf16*) alloc((size_t)3*D_*D_*2);
  float* bcat  = (float*)alloc((size_t)3*D_*4);
  bf16*  WoT   = (bf16*) alloc((size_t)D_*D_*2);
  bf16*  W1T   = (bf16*) alloc((size_t)F_*D_*2);
  bf16*  W2T   = (bf16*) alloc((size_t)D_*F_*2);
  bf16*  r1    = (bf16*) alloc((size_t)NTOK*F_*2);     // q,k,vt then ff1
  bf16*  qb    = r1;
  bf16*  kb    = r1 + (size_t)NTOK*D_;
  _Float16* vt = (_Float16*)(r1 + (size_t)2*NTOK*D_);  // [bh*64+d][S], f16, key-permuted
  bf16*  ff1   = r1;
  bf16*  ctxb  = (bf16*) alloc((size_t)NTOK*D_*2);     // ctx then y2
  bf16*  y1    = (bf16*) alloc((size_t)NTOK*D_*2);
  bf16*  hb    = (bf16*) alloc((size_t)NTOK*D_*2);
  bf16*  y2    = ctxb;

  f32_to_bf16_k<<<(NTOK*D_+255)/256, 256, 0, stream>>>(x, xb, NTOK*D_);
  transpose_f32_bf16_k<<<dim3(D_/32, D_/32), 256, 0, stream>>>(Wo, WoT, D_, D_);
  transpose_f32_bf16_k<<<dim3(F_/32, D_/32), 256, 0, stream>>>(W1, W1T, D_, F_);
  transpose_f32_bf16_k<<<dim3(D_/32, F_/32), 256, 0, stream>>>(W2, W2T, F_, D_);
  pack_qkv_t_k<<<(3*D_*D_+255)/256, 256, 0, stream>>>(Wq,bq,Wk,bk,Wv,bv,WcatT,bcat);

  // 1) fused QKV projection (q pre-scaled 1/8; v written transposed+permuted f16)
  mgemm_k<0><<<dim3(3*D_/128, NTOK/128), 256, 0, stream>>>(
      xb, WcatT, bcat, nullptr, nullptr, NTOK, 3*D_, D_, qb, kb, vt);

  // 2) MFMA flash attention -> ctx [8192,768]
  fattn_k<<<dim3(BH_, S_/64), 256, 0, stream>>>(qb, kb, vt, ctxb);

  // 3) out-proj + residual: y1 = ctx@Wo + bo + x
  mgemm_k<1><<<dim3(D_/128, NTOK/128), 256, 0, stream>>>(
      ctxb, WoT, bo, xb, y1, NTOK, D_, D_, nullptr, nullptr, nullptr);

  // 4) LN1 -> h
  layernorm_k<bf16><<<NTOK, 256, 0, stream>>>(y1, g1, be1, hb);

  // 5) FF1 + exact GELU
  mgemm_k<2><<<dim3(F_/128, NTOK/128), 256, 0, stream>>>(
      hb, W1T, b1, nullptr, ff1, NTOK, F_, D_, nullptr, nullptr, nullptr);

  // 6) FF2 + residual: y2 = ff1@W2 + b2 + h
  mgemm_k<1><<<dim3(D_/128, NTOK/128), 256, 0, stream>>>(
      ff1, W2T, b2, hb, y2, NTOK, D_, F_, nullptr, nullptr, nullptr);

  // 7) LN2 -> out (fp32)
  layernorm_k<float><<<NTOK, 256, 0, stream>>>(y2, g2, be2, out);
}